// Round 10
// baseline (173.362 us; speedup 1.0000x reference)
//
#include <hip/hip_runtime.h>
#include <math.h>

#define N_ROWS 16384
#define M_COLS 8192
#define TPB 256
#define IT 4                        // i-rows per thread
#define JT 64                       // j-tile per block
#define JU 4                        // j-unroll (staged bodies)
#define NJ (M_COLS / JT)            // 128 j-chunks
#define NIB (N_ROWS / (TPB * IT))   // 16 i-blocks
#define PAIR_BLOCKS (NIB * NJ)      // 2048 (8 blocks/CU)
#define EDGE_BLOCKS 2048
#define EU 4

typedef _Float16 h8 __attribute__((ext_vector_type(8)));

#define C2 2.0813689810056077f      // log2(e)^2 — folded into the quadratic form

// ---------- kernel 1: fused row softmax for BOTH z and w ----------
__global__ __launch_bounds__(TPB) void rownorm_kernel(
    const float* __restrict__ lz, const float* __restrict__ gr,
    const float* __restrict__ lw, const float* __restrict__ gc,
    float* __restrict__ z, float* __restrict__ zz, float* __restrict__ eg,
    _Float16* __restrict__ zh,
    float* __restrict__ w, float* __restrict__ ww, float* __restrict__ ec,
    _Float16* __restrict__ wh)
{
    int gi = blockIdx.x * TPB + threadIdx.x;
    const float *src, *g;
    float *dv, *dq, *de;
    _Float16* dh;
    int i;
    if (gi < N_ROWS) { src = lz; g = gr; dv = z; dq = zz; de = eg; dh = zh; i = gi; }
    else             { src = lw; g = gc; dv = w; dq = ww; de = ec; dh = wh; i = gi - N_ROWS; }

    const float4* sp = (const float4*)(src + (size_t)i * 8);
    float4 a = sp[0], b = sp[1];
    float v[8] = {a.x, a.y, a.z, a.w, b.x, b.y, b.z, b.w};
    float m = v[0];
    #pragma unroll
    for (int d = 1; d < 8; d++) m = fmaxf(m, v[d]);
    float s = 0.f;
    #pragma unroll
    for (int d = 0; d < 8; d++) { v[d] = __expf(v[d] - m); s += v[d]; }
    float inv = 1.f / s;
    float sq = 0.f;
    h8 hv;
    #pragma unroll
    for (int d = 0; d < 8; d++) {
        v[d] *= inv;
        sq = fmaf(v[d], v[d], sq);
        hv[d] = (_Float16)v[d];
    }
    float4 o0 = {v[0], v[1], v[2], v[3]};
    float4 o1 = {v[4], v[5], v[6], v[7]};
    float4* dp = (float4*)(dv + (size_t)i * 8);
    dp[0] = o0; dp[1] = o1;
    *(h8*)(dh + (size_t)i * 8) = hv;
    dq[i] = C2 * sq;                 // pre-scaled for the exp2 trick
    de[i] = __expf(g[i]);
}

// ---------- kernel 2: FULL pair, variant A (no LDS, uniform s_load w) ----
// S1 = sum_ij eg_i * exp(-dist_ij) * ec_j.
// w rows / ww / ec read with wave-uniform indices -> SMEM/SGPR broadcast;
// DS pipe entirely out of the loop. Staged JU=4 -> 16 independent bodies
// per stage (dots | sqrt | exp | acc).
__global__ __launch_bounds__(TPB) void pair_kernel(
    const float* __restrict__ z, const float* __restrict__ zz,
    const float* __restrict__ eg,
    const float* __restrict__ w, const float* __restrict__ ww,
    const float* __restrict__ ec,
    double* __restrict__ pair_part)
{
    __shared__ double sred[TPB];
    const int t   = threadIdx.x;
    const int rid = blockIdx.x;
    const int ib  = rid / NJ;           // 0..15
    const int jb  = rid - ib * NJ;      // 0..127
    const int j0  = jb * JT;

    float zi[IT][8], zzi[IT], acc[IT];
    const int ibase = ib * (TPB * IT);
    #pragma unroll
    for (int k = 0; k < IT; k++) {
        int i = ibase + k * TPB + t;
        const float4* zp = (const float4*)(z + (size_t)i * 8);
        float4 a = zp[0], b = zp[1];
        zi[k][0] = -2.f * C2 * a.x; zi[k][1] = -2.f * C2 * a.y;
        zi[k][2] = -2.f * C2 * a.z; zi[k][3] = -2.f * C2 * a.w;
        zi[k][4] = -2.f * C2 * b.x; zi[k][5] = -2.f * C2 * b.y;
        zi[k][6] = -2.f * C2 * b.z; zi[k][7] = -2.f * C2 * b.w;
        zzi[k] = zz[i];
        acc[k] = 0.f;
    }

    const float* wb  = w  + (size_t)j0 * 8;   // uniform base
    const float* wqb = ww + j0;
    const float* ecb = ec + j0;

    for (int jo = 0; jo < JT; jo += JU) {
        // stage 0: wave-uniform loads (scalar pipe)
        float wv[JU][8], wq[JU], ev[JU];
        #pragma unroll
        for (int u = 0; u < JU; u++) {
            #pragma unroll
            for (int d = 0; d < 8; d++) wv[u][d] = wb[(jo + u) * 8 + d];
            wq[u] = wqb[jo + u];
            ev[u] = ecb[jo + u];
        }
        // stage 1: 16 independent dot-chains (SGPR srcs fold into v_fma)
        float sq[JU][IT];
        #pragma unroll
        for (int u = 0; u < JU; u++) {
            #pragma unroll
            for (int k = 0; k < IT; k++) {
                float p = zzi[k] + wq[u];
                #pragma unroll
                for (int d = 0; d < 8; d++) p = fmaf(zi[k][d], wv[u][d], p);
                sq[u][k] = fmaxf(p, 0.f);
            }
        }
        // stage 2: 16 sqrt (trans pipe, back-to-back)
        float dd[JU][IT];
        #pragma unroll
        for (int u = 0; u < JU; u++)
            #pragma unroll
            for (int k = 0; k < IT; k++)
                asm("v_sqrt_f32 %0, %1" : "=v"(dd[u][k]) : "v"(sq[u][k]));
        // stage 3: 16 exp2(-x)
        float pr[JU][IT];
        #pragma unroll
        for (int u = 0; u < JU; u++)
            #pragma unroll
            for (int k = 0; k < IT; k++)
                asm("v_exp_f32 %0, -%1" : "=v"(pr[u][k]) : "v"(dd[u][k]));
        // stage 4: accumulate
        #pragma unroll
        for (int u = 0; u < JU; u++)
            #pragma unroll
            for (int k = 0; k < IT; k++)
                acc[k] = fmaf(ev[u], pr[u][k], acc[k]);
    }

    double tp = 0.0;
    #pragma unroll
    for (int k = 0; k < IT; k++) {
        int i = ibase + k * TPB + t;
        tp += (double)eg[i] * (double)acc[k];
    }
    sred[t] = tp;
    __syncthreads();
    for (int s = TPB / 2; s > 0; s >>= 1) {
        if (t < s) sred[t] += sred[t + s];
        __syncthreads();
    }
    if (t == 0) pair_part[rid] = sred[0];
}

// ---------- kernel 3: standalone edge ----------
__global__ __launch_bounds__(TPB) void edge_kernel(
    const _Float16* __restrict__ zh, const _Float16* __restrict__ wh,
    const float* __restrict__ gr, const float* __restrict__ gc,
    const float* __restrict__ wt,
    const int* __restrict__ ridx, const int* __restrict__ cidx, int E,
    double* __restrict__ edge_part)
{
    __shared__ double sred[TPB];
    const int t   = threadIdx.x;
    const int tid = blockIdx.x * TPB + t;
    const int e0  = tid * EU;                     // E % 4 == 0
    double local = 0.0;
    if (e0 < E) {
        int4   rr  = *(const int4*)(ridx + e0);
        int4   cc  = *(const int4*)(cidx + e0);
        float4 wt4 = *(const float4*)(wt + e0);
        int   r[EU]  = {rr.x, rr.y, rr.z, rr.w};
        int   c[EU]  = {cc.x, cc.y, cc.z, cc.w};
        float wv[EU] = {wt4.x, wt4.y, wt4.z, wt4.w};
        h8 zr[EU], wr[EU];
        float grv[EU], gcv[EU];
        #pragma unroll
        for (int u = 0; u < EU; u++) {
            zr[u]  = *(const h8*)(zh + (size_t)r[u] * 8);
            wr[u]  = *(const h8*)(wh + (size_t)c[u] * 8);
            grv[u] = gr[r[u]];
            gcv[u] = gc[c[u]];
        }
        #pragma unroll
        for (int u = 0; u < EU; u++) {
            h8 dv = zr[u] - wr[u];
            float s = 0.f;
            #pragma unroll
            for (int qd = 0; qd < 8; qd++) {
                float f = (float)dv[qd];
                s = fmaf(f, f, s);
            }
            float dist;
            asm("v_sqrt_f32 %0, %1" : "=v"(dist) : "v"(s));
            local += (double)(wv[u] * (grv[u] + gcv[u] - dist));
        }
    }
    sred[t] = local;
    __syncthreads();
    for (int s2 = TPB / 2; s2 > 0; s2 >>= 1) {
        if (t < s2) sred[t] += sred[t + s2];
        __syncthreads();
    }
    if (t == 0) edge_part[blockIdx.x] = sred[0];
}

// ---------- kernel 4: final deterministic combine ----------
__global__ __launch_bounds__(TPB) void final_kernel(
    const double* __restrict__ pp, int np,
    const double* __restrict__ ep, int ne,
    float* __restrict__ out)
{
    __shared__ double sred[TPB];
    const int t = threadIdx.x;
    double s1 = 0.0, s2 = 0.0;
    for (int i = t; i < np; i += TPB) s1 += pp[i];
    for (int i = t; i < ne; i += TPB) s2 += ep[i];
    sred[t] = s1;
    __syncthreads();
    for (int s = TPB / 2; s > 0; s >>= 1) {
        if (t < s) sred[t] += sred[t + s];
        __syncthreads();
    }
    double pair_sum = sred[0];
    __syncthreads();
    sred[t] = s2;
    __syncthreads();
    for (int s = TPB / 2; s > 0; s >>= 1) {
        if (t < s) sred[t] += sred[t + s];
        __syncthreads();
    }
    if (t == 0) {
        double edge_sum = sred[0];
        double cf = exp(-1.0e-6);   // exp(-EPS) factored out of the pair term
        out[0] = (float)(cf * pair_sum - edge_sum);
    }
}

extern "C" void kernel_launch(void* const* d_in, const int* in_sizes, int n_in,
                              void* d_out, int out_size, void* d_ws, size_t ws_size,
                              hipStream_t stream)
{
    const float* gamma_rows = (const float*)d_in[0];   // [N]
    const float* gamma_cols = (const float*)d_in[1];   // [M]
    const float* latent_z   = (const float*)d_in[2];   // [N,8]
    const float* latent_w   = (const float*)d_in[3];   // [M,8]
    const float* weights    = (const float*)d_in[4];   // [E]
    const int*   rows_idx   = (const int*)d_in[5];     // [E]
    const int*   col_idx    = (const int*)d_in[6];     // [E]
    float* out = (float*)d_out;
    const int E = in_sizes[4];

    char* base = (char*)d_ws;
    size_t off = 0;
    float* z  = (float*)(base + off); off += (size_t)N_ROWS * 8 * 4;
    float* zz = (float*)(base + off); off += (size_t)N_ROWS * 4;
    float* eg = (float*)(base + off); off += (size_t)N_ROWS * 4;
    float* w  = (float*)(base + off); off += (size_t)M_COLS * 8 * 4;
    float* ww = (float*)(base + off); off += (size_t)M_COLS * 4;
    float* ec = (float*)(base + off); off += (size_t)M_COLS * 4;
    _Float16* zh = (_Float16*)(base + off); off += (size_t)N_ROWS * 8 * 2;
    _Float16* wh = (_Float16*)(base + off); off += (size_t)M_COLS * 8 * 2;
    double* pair_part = (double*)(base + off); off += (size_t)PAIR_BLOCKS * 8;
    double* edge_part = (double*)(base + off); off += (size_t)EDGE_BLOCKS * 8;
    (void)ws_size;

    rownorm_kernel<<<(N_ROWS + M_COLS) / TPB, TPB, 0, stream>>>(
        latent_z, gamma_rows, latent_w, gamma_cols,
        z, zz, eg, zh, w, ww, ec, wh);
    pair_kernel<<<PAIR_BLOCKS, TPB, 0, stream>>>(
        z, zz, eg, w, ww, ec, pair_part);
    edge_kernel<<<EDGE_BLOCKS, TPB, 0, stream>>>(
        zh, wh, gamma_rows, gamma_cols, weights, rows_idx, col_idx, E, edge_part);
    final_kernel<<<1, TPB, 0, stream>>>(pair_part, PAIR_BLOCKS,
                                        edge_part, EDGE_BLOCKS, out);
}

// Round 11
// 152.649 us; speedup vs baseline: 1.1357x; 1.1357x over previous
//
#include <hip/hip_runtime.h>
#include <math.h>

#define N_ROWS 16384
#define M_COLS 8192
#define TPB 256
#define IT 4                        // i-rows per thread
#define JT 64                       // j-tile per block
#define JU 4                        // j-unroll (16 staged bodies)
#define NJ (M_COLS / JT)            // 128 j-chunks
#define NIB (N_ROWS / (TPB * IT))   // 16 i-blocks
#define PAIR_BLOCKS (NIB * NJ)      // 2048
#define EDGE_BLOCKS 1024
#define EU 8                        // edges per thread (E = 1024*256*8 exactly)
#define GRID_BLOCKS (PAIR_BLOCKS + EDGE_BLOCKS)   // 3072

typedef float v2f __attribute__((ext_vector_type(2)));
typedef _Float16 h8 __attribute__((ext_vector_type(8)));

#define C2 2.0813689810056077f      // log2(e)^2 — folded into the quadratic form
#define ROWB 32                     // packed row stride (bytes): {8xf16, f32 gamma, pad}

// ---------- kernel 1: row softmax -> pair arrays + packed edge rows ----------
__global__ __launch_bounds__(TPB) void rownorm_kernel(
    const float* __restrict__ lz, const float* __restrict__ gr,
    const float* __restrict__ lw, const float* __restrict__ gc,
    float* __restrict__ z, float* __restrict__ zz, float* __restrict__ eg,
    char* __restrict__ zpack,
    float* __restrict__ w, float* __restrict__ ww, float* __restrict__ ec,
    char* __restrict__ wpack)
{
    int gi = blockIdx.x * TPB + threadIdx.x;
    const float *src, *g;
    float *dv, *dq, *de;
    char* dp8;
    int i;
    if (gi < N_ROWS) { src = lz; g = gr; dv = z; dq = zz; de = eg; dp8 = zpack; i = gi; }
    else             { src = lw; g = gc; dv = w; dq = ww; de = ec; dp8 = wpack; i = gi - N_ROWS; }

    const float4* sp = (const float4*)(src + (size_t)i * 8);
    float4 a = sp[0], b = sp[1];
    float v[8] = {a.x, a.y, a.z, a.w, b.x, b.y, b.z, b.w};
    float m = v[0];
    #pragma unroll
    for (int d = 1; d < 8; d++) m = fmaxf(m, v[d]);
    float s = 0.f;
    #pragma unroll
    for (int d = 0; d < 8; d++) { v[d] = __expf(v[d] - m); s += v[d]; }
    float inv = 1.f / s;
    float sq = 0.f;
    h8 hv;
    #pragma unroll
    for (int d = 0; d < 8; d++) {
        v[d] *= inv;
        sq = fmaf(v[d], v[d], sq);
        hv[d] = (_Float16)v[d];
    }
    float gam = g[i];
    float4 o0 = {v[0], v[1], v[2], v[3]};
    float4 o1 = {v[4], v[5], v[6], v[7]};
    float4* dp = (float4*)(dv + (size_t)i * 8);
    dp[0] = o0; dp[1] = o1;
    dq[i] = C2 * sq;                 // pre-scaled for the exp2 trick
    de[i] = __expf(gam);
    // packed edge row: one 128B line holds 4 rows -> row+gamma = 1 line
    char* rp = dp8 + (size_t)i * ROWB;
    *(h8*)rp = hv;
    *(float*)(rp + 16) = gam;        // raw gamma (edge term uses raw)
}

// ---------- kernel 2: fused pair + edge (edge role on bid%3==0 ... ) ----
// pair role (2048 blocks): S1 = sum_ij eg_i*exp(-dist_ij)*ec_j
//   LDS w-tile (w in VGPR -> v_pk_fma dot: 4 pk insts vs 8 scalar),
//   staged JU=4 (16 bodies: dots | sqrt | exp | acc).
// edge role (1024 blocks, EU=8): packed 32B rows -> 2 scattered lines/edge
//   (row+gamma same 128B line), 16 outstanding gathers/thread.
__global__ __launch_bounds__(TPB) void fused_kernel(
    const float* __restrict__ z, const float* __restrict__ zz,
    const float* __restrict__ eg,
    const float* __restrict__ w, const float* __restrict__ ww,
    const float* __restrict__ ec,
    const char* __restrict__ zpack, const char* __restrict__ wpack,
    const float* __restrict__ wt,
    const int* __restrict__ ridx, const int* __restrict__ cidx, int E,
    double* __restrict__ pair_part, double* __restrict__ edge_part)
{
    __shared__ float  sw[JT * 8];    // w tile [JT][8]
    __shared__ float  swq[JT];       // C2*||w_j||^2
    __shared__ float  sec[JT];       // exp(gamma_cols[j])
    __shared__ double sred[TPB];

    const int t   = threadIdx.x;
    const int bid = blockIdx.x;
    const int tri = bid / 3;
    const int rem = bid - tri * 3;

    if (rem != 0) {
        // ================= PAIR ROLE (2048 blocks) =================
        const int rid = tri * 2 + (rem - 1);     // 0..2047
        const int ib = rid / NJ;                 // 0..15
        const int jb = rid - ib * NJ;
        const int j0 = jb * JT;

        if (t < JT * 2) ((float4*)sw)[t] = ((const float4*)(w + (size_t)j0 * 8))[t];
        if (t < JT)     { swq[t] = ww[j0 + t]; sec[t] = ec[j0 + t]; }

        // z rows pre-scaled by -2*C2: sq' = (zz'+ww') + sum (-2C2 z)*w
        v2f  zi[IT][4];
        float zzi[IT], acc[IT];
        const int ibase = ib * (TPB * IT);
        #pragma unroll
        for (int k = 0; k < IT; k++) {
            int i = ibase + k * TPB + t;
            const float4* zp = (const float4*)(z + (size_t)i * 8);
            float4 a = zp[0], b = zp[1];
            zi[k][0] = (v2f){-2.f * C2 * a.x, -2.f * C2 * a.y};
            zi[k][1] = (v2f){-2.f * C2 * a.z, -2.f * C2 * a.w};
            zi[k][2] = (v2f){-2.f * C2 * b.x, -2.f * C2 * b.y};
            zi[k][3] = (v2f){-2.f * C2 * b.z, -2.f * C2 * b.w};
            zzi[k] = zz[i];
            acc[k] = 0.f;
        }
        __syncthreads();

        const float4* s4 = (const float4*)sw;
        for (int jo = 0; jo < JT; jo += JU) {
            // stage 0: batch LDS reads for 4 j's
            float4 wa[JU], wb[JU];
            float  wq[JU], ev[JU];
            #pragma unroll
            for (int u = 0; u < JU; u++) {
                wa[u] = s4[(jo + u) * 2];
                wb[u] = s4[(jo + u) * 2 + 1];
                wq[u] = swq[jo + u];
                ev[u] = sec[jo + u];
            }
            // stage 1: 16 dot-chains, pk math (pk_mul + 3 pk_fma each)
            float sq[JU][IT];
            #pragma unroll
            for (int u = 0; u < JU; u++) {
                v2f w01 = {wa[u].x, wa[u].y}, w23 = {wa[u].z, wa[u].w};
                v2f w45 = {wb[u].x, wb[u].y}, w67 = {wb[u].z, wb[u].w};
                #pragma unroll
                for (int k = 0; k < IT; k++) {
                    v2f p = zi[k][0] * w01;
                    p = __builtin_elementwise_fma(zi[k][1], w23, p);
                    p = __builtin_elementwise_fma(zi[k][2], w45, p);
                    p = __builtin_elementwise_fma(zi[k][3], w67, p);
                    sq[u][k] = fmaxf(p.x + p.y + (zzi[k] + wq[u]), 0.f);
                }
            }
            // stage 2: 16 sqrt
            float dd[JU][IT];
            #pragma unroll
            for (int u = 0; u < JU; u++)
                #pragma unroll
                for (int k = 0; k < IT; k++)
                    asm("v_sqrt_f32 %0, %1" : "=v"(dd[u][k]) : "v"(sq[u][k]));
            // stage 3: 16 exp2(-x)
            float pr[JU][IT];
            #pragma unroll
            for (int u = 0; u < JU; u++)
                #pragma unroll
                for (int k = 0; k < IT; k++)
                    asm("v_exp_f32 %0, -%1" : "=v"(pr[u][k]) : "v"(dd[u][k]));
            // stage 4: accumulate
            #pragma unroll
            for (int u = 0; u < JU; u++)
                #pragma unroll
                for (int k = 0; k < IT; k++)
                    acc[k] = fmaf(ev[u], pr[u][k], acc[k]);
        }

        double tp = 0.0;
        #pragma unroll
        for (int k = 0; k < IT; k++) {
            int i = ibase + k * TPB + t;
            tp += (double)eg[i] * (double)acc[k];
        }
        sred[t] = tp;
        __syncthreads();
        for (int s = TPB / 2; s > 0; s >>= 1) {
            if (t < s) sred[t] += sred[t + s];
            __syncthreads();
        }
        if (t == 0) pair_part[rid] = sred[0];
    } else {
        // ================= EDGE ROLE (1024 blocks) =================
        const int er  = tri;                        // 0..1023
        const int tid = er * TPB + t;
        const int e0  = tid * EU;                   // covers E exactly
        double local = 0.0;
        if (e0 < E) {
            int4   rr0 = *(const int4*)(ridx + e0);
            int4   rr1 = *(const int4*)(ridx + e0 + 4);
            int4   cc0 = *(const int4*)(cidx + e0);
            int4   cc1 = *(const int4*)(cidx + e0 + 4);
            float4 wtA = *(const float4*)(wt + e0);
            float4 wtB = *(const float4*)(wt + e0 + 4);
            int   r[EU]  = {rr0.x, rr0.y, rr0.z, rr0.w, rr1.x, rr1.y, rr1.z, rr1.w};
            int   c[EU]  = {cc0.x, cc0.y, cc0.z, cc0.w, cc1.x, cc1.y, cc1.z, cc1.w};
            float wv[EU] = {wtA.x, wtA.y, wtA.z, wtA.w, wtB.x, wtB.y, wtB.z, wtB.w};
            // issue all 16 row gathers up front (gamma rides the same line)
            h8 zr[EU], wr[EU];
            float grv[EU], gcv[EU];
            #pragma unroll
            for (int u = 0; u < EU; u++) {
                const char* zp = zpack + (size_t)r[u] * ROWB;
                const char* wp = wpack + (size_t)c[u] * ROWB;
                zr[u]  = *(const h8*)zp;
                wr[u]  = *(const h8*)wp;
                grv[u] = *(const float*)(zp + 16);
                gcv[u] = *(const float*)(wp + 16);
            }
            #pragma unroll
            for (int u = 0; u < EU; u++) {
                h8 dv = zr[u] - wr[u];
                float s = 0.f;
                #pragma unroll
                for (int qd = 0; qd < 8; qd++) {
                    float f = (float)dv[qd];
                    s = fmaf(f, f, s);
                }
                float dist;
                asm("v_sqrt_f32 %0, %1" : "=v"(dist) : "v"(s));
                local += (double)(wv[u] * (grv[u] + gcv[u] - dist));
            }
        }
        sred[t] = local;
        __syncthreads();
        for (int s2 = TPB / 2; s2 > 0; s2 >>= 1) {
            if (t < s2) sred[t] += sred[t + s2];
            __syncthreads();
        }
        if (t == 0) edge_part[er] = sred[0];
    }
}

// ---------- kernel 3: final deterministic combine ----------
__global__ __launch_bounds__(TPB) void final_kernel(
    const double* __restrict__ pp, int np,
    const double* __restrict__ ep, int ne,
    float* __restrict__ out)
{
    __shared__ double sred[TPB];
    const int t = threadIdx.x;
    double s1 = 0.0, s2 = 0.0;
    for (int i = t; i < np; i += TPB) s1 += pp[i];
    for (int i = t; i < ne; i += TPB) s2 += ep[i];
    sred[t] = s1;
    __syncthreads();
    for (int s = TPB / 2; s > 0; s >>= 1) {
        if (t < s) sred[t] += sred[t + s];
        __syncthreads();
    }
    double pair_sum = sred[0];
    __syncthreads();
    sred[t] = s2;
    __syncthreads();
    for (int s = TPB / 2; s > 0; s >>= 1) {
        if (t < s) sred[t] += sred[t + s];
        __syncthreads();
    }
    if (t == 0) {
        double edge_sum = sred[0];
        double cf = exp(-1.0e-6);   // exp(-EPS) factored out of the pair term
        out[0] = (float)(cf * pair_sum - edge_sum);
    }
}

extern "C" void kernel_launch(void* const* d_in, const int* in_sizes, int n_in,
                              void* d_out, int out_size, void* d_ws, size_t ws_size,
                              hipStream_t stream)
{
    const float* gamma_rows = (const float*)d_in[0];   // [N]
    const float* gamma_cols = (const float*)d_in[1];   // [M]
    const float* latent_z   = (const float*)d_in[2];   // [N,8]
    const float* latent_w   = (const float*)d_in[3];   // [M,8]
    const float* weights    = (const float*)d_in[4];   // [E]
    const int*   rows_idx   = (const int*)d_in[5];     // [E]
    const int*   col_idx    = (const int*)d_in[6];     // [E]
    float* out = (float*)d_out;
    const int E = in_sizes[4];

    // workspace layout (segments 256B-aligned); total ~1.8 MB
    char* base = (char*)d_ws;
    size_t off = 0;
    float* z  = (float*)(base + off); off += (size_t)N_ROWS * 8 * 4;      // 512K
    float* zz = (float*)(base + off); off += (size_t)N_ROWS * 4;          //  64K
    float* eg = (float*)(base + off); off += (size_t)N_ROWS * 4;          //  64K
    float* w  = (float*)(base + off); off += (size_t)M_COLS * 8 * 4;      // 256K
    float* ww = (float*)(base + off); off += (size_t)M_COLS * 4;          //  32K
    float* ec = (float*)(base + off); off += (size_t)M_COLS * 4;          //  32K
    char* zpack = base + off; off += (size_t)N_ROWS * ROWB;               // 512K
    char* wpack = base + off; off += (size_t)M_COLS * ROWB;               // 256K
    double* pair_part = (double*)(base + off); off += (size_t)PAIR_BLOCKS * 8;
    double* edge_part = (double*)(base + off); off += (size_t)EDGE_BLOCKS * 8;
    (void)ws_size;

    rownorm_kernel<<<(N_ROWS + M_COLS) / TPB, TPB, 0, stream>>>(
        latent_z, gamma_rows, latent_w, gamma_cols,
        z, zz, eg, zpack, w, ww, ec, wpack);
    fused_kernel<<<GRID_BLOCKS, TPB, 0, stream>>>(
        z, zz, eg, w, ww, ec, zpack, wpack,
        weights, rows_idx, col_idx, E, pair_part, edge_part);
    final_kernel<<<1, TPB, 0, stream>>>(pair_part, PAIR_BLOCKS,
                                        edge_part, EDGE_BLOCKS, out);
}